// Round 6
// baseline (5926.572 us; speedup 1.0000x reference)
//
#include <hip/hip_runtime.h>

// R6: layer-split producer/consumer LSTM with TWO independent batch-group
// streams per block (ILP to fill latency-exposure).
//  - 16 blocks x 512 threads: blocks 0..7 = L0 producers, 8..15 = L1 consumers.
//    pair = blockIdx&7 owns batch groups gA=2*pair, gB=2*pair+1 (16 batches each).
//  - Producer streams h0(t) of both groups through rings in d_ws (RING=32).
//    One flag per pair per step (after BOTH streams). Consumer publishes every 8.
//  - Consumer JIT-loads ring slots (poll prodf>=t+1); stream B's loads/MFMAs
//    hide stream A's latency and vice versa. One barrier per step-pair.
//  - L1 biases live in LDS (f32 D-frag image) to keep consumer regs < 256.
//  - Fallback: proven R2 single-kernel path if ws_size too small.

typedef short bf16x8 __attribute__((ext_vector_type(8)));
typedef float f32x4 __attribute__((ext_vector_type(4)));

static constexpr int CIN = 12, T = 2048, H = 128;
static constexpr int NTHR = 512;
static constexpr float L2E = 1.4426950408889634f;

static constexpr int RING = 32;                   // ring slots per group
static constexpr size_t SLOT_BYTES = 4096;        // 16 batches x 128 cols x 2B
static constexpr size_t FLAG_BYTES = 8192;        // prod[8]+cons[8], 256B stride
static constexpr size_t WS_NEED = FLAG_BYTES + 16ull * RING * SLOT_BYTES;  // ~2.1MB

#if __has_builtin(__builtin_amdgcn_exp2f)
#define EXP2(x) __builtin_amdgcn_exp2f(x)
#else
#define EXP2(x) exp2f(x)
#endif

__device__ __forceinline__ unsigned f2bf(float f) {  // f32 -> bf16 bits, RTNE (prologue only)
  unsigned u = __builtin_bit_cast(unsigned, f);
  return (u + 0x7FFFu + ((u >> 16) & 1u)) >> 16;
}

__device__ __forceinline__ unsigned cvtpk_bf16(float lo, float hi) {
  unsigned r;
  asm("v_cvt_pk_bf16_f32 %0, %1, %2" : "=v"(r) : "v"(lo), "v"(hi));
  return r;
}

__device__ __forceinline__ float sig_pre(float a) {  // 1/(1+2^a)
  return __builtin_amdgcn_rcpf(1.f + EXP2(a));
}

// Gate math on a D-fragment (4 rows/lane); weights pre-scaled (i,f,o * -log2e,
// g * 2log2e). Updates c[], h[]; returns packed 4x bf16 of h.
__device__ __forceinline__ unsigned long long lstm_ew(
    const f32x4& a0, const f32x4& a1, const f32x4& a2, const f32x4& a3,
    float* cv, float* hv) {
  #pragma unroll
  for (int r = 0; r < 4; ++r) {
    const float iv = sig_pre(a0[r]);
    const float fv = sig_pre(a1[r]);
    const float gv = fmaf(-2.f, sig_pre(a2[r]), 1.f);
    const float ov = sig_pre(a3[r]);
    const float c  = fmaf(fv, cv[r], iv * gv);
    cv[r] = c;
    const float th = fmaf(-2.f, sig_pre(c * (2.f * L2E)), 1.f);
    hv[r] = ov * th;
  }
  const unsigned hp0 = cvtpk_bf16(hv[0], hv[1]);
  const unsigned hp1 = cvtpk_bf16(hv[2], hv[3]);
  return ((unsigned long long)hp1 << 32) | hp0;
}

__device__ __forceinline__ void wait_ge(unsigned* p, unsigned tgt) {
  while (__hip_atomic_load(p, __ATOMIC_ACQUIRE, __HIP_MEMORY_SCOPE_AGENT) < tgt)
    __builtin_amdgcn_s_sleep(1);
}

__global__ void lstm_zero_flags(unsigned* f) {
  f[blockIdx.x * 256 + threadIdx.x] = 0;  // 8 blocks x 256 = 8KB
}

// ============================ split kernel ============================
__global__ __launch_bounds__(NTHR, 2) void lstm_split2(
    const float* __restrict__ xg,
    const float* __restrict__ Wih0, const float* __restrict__ Whh0,
    const float* __restrict__ bih0, const float* __restrict__ bhh0,
    const float* __restrict__ Wih1, const float* __restrict__ Whh1,
    const float* __restrict__ bih1, const float* __restrict__ bhh1,
    const float* __restrict__ Wd,   const float* __restrict__ bd,
    float* __restrict__ out, char* __restrict__ ws)
{
  __shared__ char lds[22528];
  const int tid = threadIdx.x;
  const int l  = tid & 63;
  const int w  = tid >> 6;   // wave 0..7
  const int lg = l >> 4;     // lane group 0..3 (k-chunk)
  const int lr = l & 15;     // A: row-in-tile ; B/D: batch column
  const bool producer = (blockIdx.x < 8);
  const int pair = blockIdx.x & 7;
  const int b0A = pair * 32, b0B = pair * 32 + 16;

  unsigned* prodf = (unsigned*)ws + pair * 64;          // 256B stride
  unsigned* consf = (unsigned*)ws + 1024 + pair * 64;
  char* ringA = ws + FLAG_BYTES + (size_t)(pair * 2)     * RING * SLOT_BYTES;
  char* ringB = ws + FLAG_BYTES + (size_t)(pair * 2 + 1) * RING * SLOT_BYTES;

  for (int i = tid; i < 22528 / 4; i += NTHR) ((int*)lds)[i] = 0;
  __syncthreads();

  // shared per-lane geometry
  const int rdB  = lg * 256 + lr * 16;                  // B-frag read base
  const int bcol = w * 16 + lg * 4;                     // base h-column (4/lane)
  const int wrH  = (bcol >> 3) * 256 + lr * 16 + (bcol & 7) * 2;

  if (producer) {
    // ---------------- LAYER 0 PRODUCER (2 streams) ----------------
    // LDS: H0A dbuf @0 (2x4096), H0B @8192, XA dbuf @16384 (2x1024), XB @18432
    constexpr int XOFF = 16384;
    if (tid < 64) {  // const-1.0 column at k==12: 2 groups x 2 bufs
      const int g = tid >> 5, buf = (tid >> 4) & 1, b = tid & 15;
      *(unsigned short*)(lds + XOFF + g * 2048 + buf * 1024 + 256 + b * 16 + 8) = 0x3F80;
    }

    bf16x8 A0[4][5];
    #pragma unroll
    for (int q = 0; q < 4; ++q) {
      const int n = (q * 8 + w) * 16 + lr;
      const float s = (q == 2) ? (2.f * L2E) : (-L2E);
      #pragma unroll
      for (int kf = 0; kf < 4; ++kf) {
        const float* src = &Whh0[n * H + kf * 32 + lg * 8];
        #pragma unroll
        for (int j = 0; j < 8; ++j) A0[q][kf][j] = (short)f2bf(src[j] * s);
      }
      #pragma unroll
      for (int j = 0; j < 8; ++j) {
        const int k = lg * 8 + j;
        float v = 0.f;
        if (k < CIN) v = Wih0[n * CIN + k] * s;
        else if (k == CIN) v = (bih0[n] + bhh0[n]) * s;
        A0[q][4][j] = (short)f2bf(v);
      }
    }
    const f32x4 zed = {0.f, 0.f, 0.f, 0.f};

    // x loader roles: threads 0..191 -> group A, 256..447 -> group B
    const int uA = tid, uB = tid - 256;
    const bool ldA = (tid < 192), ldB = (tid >= 256 && tid < 448);
    const int xbA = uA & 15, xcA = uA >> 4;
    const int xbB = uB & 15, xcB = uB >> 4;
    const int wrXA = (xcA >> 3) * 256 + xbA * 16 + (xcA & 7) * 2;
    const int wrXB = (xcB >> 3) * 256 + xbB * 16 + (xcB & 7) * 2;
    const size_t xbaseA = (size_t)(b0A + xbA) * (CIN * T) + (size_t)xcA * T;
    const size_t xbaseB = (size_t)(b0B + xbB) * (CIN * T) + (size_t)xcB * T;
    if (ldA) *(unsigned short*)(lds + XOFF + wrXA) = (unsigned short)f2bf(xg[xbaseA]);
    if (ldB) *(unsigned short*)(lds + XOFF + 2048 + wrXB) = (unsigned short)f2bf(xg[xbaseB]);
    __syncthreads();

    float c0A[4] = {0.f, 0.f, 0.f, 0.f};
    float c0B[4] = {0.f, 0.f, 0.f, 0.f};
    float h0t[4];
    unsigned cons_seen = 0;

    #pragma unroll 2
    for (int t = 0; t < T; ++t) {
      const int p = t & 1;
      if (t >= RING) {
        const unsigned tgt = (unsigned)(t - RING + 1);
        if (cons_seen < tgt) { wait_ge(consf, tgt); cons_seen = tgt; }
      }
      float xnA = 0.f, xnB = 0.f;
      const int tn = (t + 1 < T) ? t + 1 : t;
      if (ldA) xnA = xg[xbaseA + tn];
      if (ldB) xnB = xg[xbaseB + tn];

      // ---- stream A ----
      {
        bf16x8 bf0[4], bfX;
        #pragma unroll
        for (int kf = 0; kf < 4; ++kf)
          bf0[kf] = *(const bf16x8*)(lds + p * 4096 + kf * 1024 + rdB);
        bfX = *(const bf16x8*)(lds + XOFF + p * 1024 + rdB);
        f32x4 acc[4];
        #pragma unroll
        for (int q = 0; q < 4; ++q) acc[q] = zed;
        #pragma unroll
        for (int kf = 0; kf < 4; ++kf)
          #pragma unroll
          for (int q = 0; q < 4; ++q)
            acc[q] = __builtin_amdgcn_mfma_f32_16x16x32_bf16(A0[q][kf], bf0[kf], acc[q], 0, 0, 0);
        #pragma unroll
        for (int q = 0; q < 4; ++q)
          acc[q] = __builtin_amdgcn_mfma_f32_16x16x32_bf16(A0[q][4], bfX, acc[q], 0, 0, 0);
        const unsigned long long hv64 = lstm_ew(acc[0], acc[1], acc[2], acc[3], c0A, h0t);
        *(unsigned long long*)(lds + (1 - p) * 4096 + wrH) = hv64;
        *(unsigned long long*)(ringA + (size_t)(t & (RING - 1)) * SLOT_BYTES + wrH) = hv64;
      }
      // ---- stream B ----
      {
        bf16x8 bf0[4], bfX;
        #pragma unroll
        for (int kf = 0; kf < 4; ++kf)
          bf0[kf] = *(const bf16x8*)(lds + 8192 + p * 4096 + kf * 1024 + rdB);
        bfX = *(const bf16x8*)(lds + XOFF + 2048 + p * 1024 + rdB);
        f32x4 acc[4];
        #pragma unroll
        for (int q = 0; q < 4; ++q) acc[q] = zed;
        #pragma unroll
        for (int kf = 0; kf < 4; ++kf)
          #pragma unroll
          for (int q = 0; q < 4; ++q)
            acc[q] = __builtin_amdgcn_mfma_f32_16x16x32_bf16(A0[q][kf], bf0[kf], acc[q], 0, 0, 0);
        #pragma unroll
        for (int q = 0; q < 4; ++q)
          acc[q] = __builtin_amdgcn_mfma_f32_16x16x32_bf16(A0[q][4], bfX, acc[q], 0, 0, 0);
        const unsigned long long hv64 = lstm_ew(acc[0], acc[1], acc[2], acc[3], c0B, h0t);
        *(unsigned long long*)(lds + 8192 + (1 - p) * 4096 + wrH) = hv64;
        *(unsigned long long*)(ringB + (size_t)(t & (RING - 1)) * SLOT_BYTES + wrH) = hv64;
      }
      if (ldA) *(unsigned short*)(lds + XOFF + (1 - p) * 1024 + wrXA) =
          (unsigned short)cvtpk_bf16(xnA, xnA);
      if (ldB) *(unsigned short*)(lds + XOFF + 2048 + (1 - p) * 1024 + wrXB) =
          (unsigned short)cvtpk_bf16(xnB, xnB);
      __syncthreads();   // drains ring stores (vmcnt) before flag
      if (tid == 0)
        __hip_atomic_store(prodf, (unsigned)(t + 1), __ATOMIC_RELEASE, __HIP_MEMORY_SCOPE_AGENT);
    }
    return;
  }

  // ---------------- LAYER 1 CONSUMER (2 streams) ----------------
  // LDS: H1A dbuf @0 (2x4096), H1B @8192, b1 f32 image @16384 (2KB),
  //      REDA @18432 (2KB), REDB @20480 (2KB)
  constexpr int B1OFF = 16384, REDA = 18432, REDB = 20480;
  bf16x8 A1[4][8];
  #pragma unroll
  for (int q = 0; q < 4; ++q) {
    const int n = (q * 8 + w) * 16 + lr;
    const float s = (q == 2) ? (2.f * L2E) : (-L2E);
    #pragma unroll
    for (int kf = 0; kf < 4; ++kf) {
      const float* srcA = &Whh1[n * H + kf * 32 + lg * 8];
      const float* srcB = &Wih1[n * H + kf * 32 + lg * 8];
      #pragma unroll
      for (int j = 0; j < 8; ++j) {
        A1[q][kf][j]     = (short)f2bf(srcA[j] * s);
        A1[q][4 + kf][j] = (short)f2bf(srcB[j] * s);
      }
    }
  }
  {  // L1 bias as f32 D-frag image in LDS (row n at B1OFF + 4n)
    const int n = tid;
    const float s = ((n >> 7) == 2) ? (2.f * L2E) : (-L2E);
    ((float*)(lds + B1OFF))[n] = (bih1[n] + bhh1[n]) * s;
  }
  __syncthreads();

  const int bq0 = ((0 * 8 + w) * 16 + lg * 4) * 4;  // byte offsets of b1 rows per q
  float c1A[4] = {0.f, 0.f, 0.f, 0.f}, h1A[4] = {0.f, 0.f, 0.f, 0.f};
  float c1B[4] = {0.f, 0.f, 0.f, 0.f}, h1B[4] = {0.f, 0.f, 0.f, 0.f};
  unsigned prod_seen = 0;

  #pragma unroll 2
  for (int t = 0; t < T; ++t) {
    const int P = t & 1;
    const unsigned need = (unsigned)(t + 1);
    if (prod_seen < need) { wait_ge(prodf, need); prod_seen = need; }
    const char* slotA = ringA + (size_t)(t & (RING - 1)) * SLOT_BYTES;
    const char* slotB = ringB + (size_t)(t & (RING - 1)) * SLOT_BYTES;
    bf16x8 curA[4], curB[4];
    #pragma unroll
    for (int kf = 0; kf < 4; ++kf) curA[kf] = *(const bf16x8*)(slotA + kf * 1024 + rdB);
    #pragma unroll
    for (int kf = 0; kf < 4; ++kf) curB[kf] = *(const bf16x8*)(slotB + kf * 1024 + rdB);

    // ---- stream A ----
    {
      bf16x8 bh1[4];
      #pragma unroll
      for (int kf = 0; kf < 4; ++kf)
        bh1[kf] = *(const bf16x8*)(lds + P * 4096 + kf * 1024 + rdB);
      f32x4 acc[4];
      #pragma unroll
      for (int q = 0; q < 4; ++q)
        acc[q] = *(const f32x4*)(lds + B1OFF + bq0 + q * 512);
      #pragma unroll
      for (int kf = 0; kf < 4; ++kf)
        #pragma unroll
        for (int q = 0; q < 4; ++q) {
          acc[q] = __builtin_amdgcn_mfma_f32_16x16x32_bf16(A1[q][kf], bh1[kf], acc[q], 0, 0, 0);
          acc[q] = __builtin_amdgcn_mfma_f32_16x16x32_bf16(A1[q][4 + kf], curA[kf], acc[q], 0, 0, 0);
        }
      const unsigned long long hv64 = lstm_ew(acc[0], acc[1], acc[2], acc[3], c1A, h1A);
      *(unsigned long long*)(lds + (1 - P) * 4096 + wrH) = hv64;
    }
    // ---- stream B ----
    {
      bf16x8 bh1[4];
      #pragma unroll
      for (int kf = 0; kf < 4; ++kf)
        bh1[kf] = *(const bf16x8*)(lds + 8192 + P * 4096 + kf * 1024 + rdB);
      f32x4 acc[4];
      #pragma unroll
      for (int q = 0; q < 4; ++q)
        acc[q] = *(const f32x4*)(lds + B1OFF + bq0 + q * 512);
      #pragma unroll
      for (int kf = 0; kf < 4; ++kf)
        #pragma unroll
        for (int q = 0; q < 4; ++q) {
          acc[q] = __builtin_amdgcn_mfma_f32_16x16x32_bf16(A1[q][kf], bh1[kf], acc[q], 0, 0, 0);
          acc[q] = __builtin_amdgcn_mfma_f32_16x16x32_bf16(A1[q][4 + kf], curB[kf], acc[q], 0, 0, 0);
        }
      const unsigned long long hv64 = lstm_ew(acc[0], acc[1], acc[2], acc[3], c1B, h1B);
      *(unsigned long long*)(lds + 8192 + (1 - P) * 4096 + wrH) = hv64;
    }
    __syncthreads();
    if (tid == 0 && (((t + 1) & 7) == 0))
      __hip_atomic_store(consf, (unsigned)(t + 1), __ATOMIC_RELEASE, __HIP_MEMORY_SCOPE_AGENT);
  }

  // ---- epilogue ----
  const float4 wd = *(const float4*)&Wd[bcol];
  const float pA = h1A[0] * wd.x + h1A[1] * wd.y + h1A[2] * wd.z + h1A[3] * wd.w;
  const float pB = h1B[0] * wd.x + h1B[1] * wd.y + h1B[2] * wd.z + h1B[3] * wd.w;
  #pragma unroll
  for (int r = 0; r < 4; ++r) {
    out[256 + (size_t)(b0A + lr) * H + (bcol + r)] = h1A[r];
    out[256 + (size_t)(b0B + lr) * H + (bcol + r)] = h1B[r];
  }
  ((float*)(lds + REDA))[tid] = pA;
  ((float*)(lds + REDB))[tid] = pB;
  __syncthreads();
  if (tid < 16) {
    float s = 0.f;
    #pragma unroll 8
    for (int k = 0; k < 32; ++k) s += ((float*)(lds + REDA))[tid + 16 * k];
    out[b0A + tid] = __builtin_amdgcn_rcpf(1.f + EXP2(-(s + bd[0]) * L2E));
  } else if (tid < 32) {
    float s = 0.f;
    #pragma unroll 8
    for (int k = 0; k < 32; ++k) s += ((float*)(lds + REDB))[(tid - 16) + 16 * k];
    out[b0B + (tid - 16)] = __builtin_amdgcn_rcpf(1.f + EXP2(-(s + bd[0]) * L2E));
  }
}

// ============================ fallback: R2 single kernel ============================
__global__ __launch_bounds__(NTHR, 2) void lstm_single(
    const float* __restrict__ xg,
    const float* __restrict__ Wih0, const float* __restrict__ Whh0,
    const float* __restrict__ bih0, const float* __restrict__ bhh0,
    const float* __restrict__ Wih1, const float* __restrict__ Whh1,
    const float* __restrict__ bih1, const float* __restrict__ bhh1,
    const float* __restrict__ Wd,   const float* __restrict__ bd,
    float* __restrict__ out)
{
  constexpr int LDS_H0 = 0, LDS_H1 = 8192, LDS_X = 16384, LDS_RED = 18432, LDS_SZ = 20480;
  __shared__ char lds[LDS_SZ];
  const int tid = threadIdx.x;
  const int l  = tid & 63;
  const int w  = tid >> 6;
  const int lg = l >> 4;
  const int lr = l & 15;
  const int b0 = blockIdx.x * 16;

  for (int i = tid; i < LDS_SZ / 4; i += NTHR) ((int*)lds)[i] = 0;
  __syncthreads();
  if (tid < 32) {
    const int buf = tid >> 4, b = tid & 15;
    *(unsigned short*)(lds + LDS_X + buf * 1024 + 256 + b * 16 + 8) = 0x3F80;
  }

  bf16x8 A0[4][5];
  bf16x8 A1[4][8];
  f32x4 b1r[4];
  #pragma unroll
  for (int q = 0; q < 4; ++q) {
    const int n = (q * 8 + w) * 16 + lr;
    const float s = (q == 2) ? (2.f * L2E) : (-L2E);
    #pragma unroll
    for (int kf = 0; kf < 4; ++kf) {
      const float* src = &Whh0[n * H + kf * 32 + lg * 8];
      #pragma unroll
      for (int j = 0; j < 8; ++j) A0[q][kf][j] = (short)f2bf(src[j] * s);
    }
    #pragma unroll
    for (int j = 0; j < 8; ++j) {
      const int k = lg * 8 + j;
      float v = 0.f;
      if (k < CIN) v = Wih0[n * CIN + k] * s;
      else if (k == CIN) v = (bih0[n] + bhh0[n]) * s;
      A0[q][4][j] = (short)f2bf(v);
    }
    #pragma unroll
    for (int kf = 0; kf < 4; ++kf) {
      const float* srcA = &Whh1[n * H + kf * 32 + lg * 8];
      const float* srcB = &Wih1[n * H + kf * 32 + lg * 8];
      #pragma unroll
      for (int j = 0; j < 8; ++j) {
        A1[q][kf][j]     = (short)f2bf(srcA[j] * s);
        A1[q][4 + kf][j] = (short)f2bf(srcB[j] * s);
      }
    }
    #pragma unroll
    for (int r = 0; r < 4; ++r) {
      const int nd = (q * 8 + w) * 16 + lg * 4 + r;
      b1r[q][r] = (bih1[nd] + bhh1[nd]) * s;
    }
  }
  const f32x4 zed = {0.f, 0.f, 0.f, 0.f};

  const int rdB  = lg * 256 + lr * 16;
  const int bcol = w * 16 + lg * 4;
  const int wrH  = (bcol >> 3) * 256 + lr * 16 + (bcol & 7) * 2;
  const int xb = tid & 15, xc = tid >> 4;
  const int wrX = (xc >> 3) * 256 + xb * 16 + (xc & 7) * 2;
  const size_t xbase = (size_t)(b0 + xb) * (CIN * T) + (size_t)xc * T;

  if (tid < 192)
    *(unsigned short*)(lds + LDS_X + wrX) = (unsigned short)f2bf(xg[xbase]);
  __syncthreads();

  float c0v[4] = {0.f, 0.f, 0.f, 0.f};
  float c1v[4] = {0.f, 0.f, 0.f, 0.f};
  float h1v[4] = {0.f, 0.f, 0.f, 0.f};
  float h0t[4];

  #pragma unroll 2
  for (int t = 0; t < T; ++t) {
    const int p = t & 1;
    float xnext = 0.f;
    if (tid < 192) xnext = xg[xbase + (t + 1 < T ? t + 1 : t)];

    f32x4 acc[4];
    #pragma unroll
    for (int q = 0; q < 4; ++q) acc[q] = zed;
    #pragma unroll
    for (int kf = 0; kf < 5; ++kf) {
      const int src = (kf < 4) ? (LDS_H0 + p * 4096 + kf * 1024 + rdB)
                               : (LDS_X + p * 1024 + rdB);
      const bf16x8 bf = *(const bf16x8*)(lds + src);
      #pragma unroll
      for (int q = 0; q < 4; ++q)
        acc[q] = __builtin_amdgcn_mfma_f32_16x16x32_bf16(A0[q][kf], bf, acc[q], 0, 0, 0);
    }
    *(unsigned long long*)(lds + LDS_H0 + (1 - p) * 4096 + wrH) =
        lstm_ew(acc[0], acc[1], acc[2], acc[3], c0v, h0t);
    if (tid < 192) {
      const unsigned xp = cvtpk_bf16(xnext, xnext);
      *(unsigned short*)(lds + LDS_X + (1 - p) * 1024 + wrX) = (unsigned short)xp;
    }
    __syncthreads();

    #pragma unroll
    for (int q = 0; q < 4; ++q) acc[q] = b1r[q];
    #pragma unroll
    for (int kf = 0; kf < 8; ++kf) {
      const int src = (kf < 4)
          ? (LDS_H1 + p * 4096 + kf * 1024 + rdB)
          : (LDS_H0 + (1 - p) * 4096 + (kf - 4) * 1024 + rdB);
      const bf16x8 bf = *(const bf16x8*)(lds + src);
      #pragma unroll
      for (int q = 0; q < 4; ++q)
        acc[q] = __builtin_amdgcn_mfma_f32_16x16x32_bf16(A1[q][kf], bf, acc[q], 0, 0, 0);
    }
    *(unsigned long long*)(lds + LDS_H1 + (1 - p) * 4096 + wrH) =
        lstm_ew(acc[0], acc[1], acc[2], acc[3], c1v, h1v);
    __syncthreads();
  }

  const float4 wd = *(const float4*)&Wd[bcol];
  const float partial = h1v[0] * wd.x + h1v[1] * wd.y + h1v[2] * wd.z + h1v[3] * wd.w;
  #pragma unroll
  for (int r = 0; r < 4; ++r)
    out[256 + (size_t)(b0 + lr) * H + (bcol + r)] = h1v[r];
  ((float*)(lds + LDS_RED))[tid] = partial;
  __syncthreads();
  if (tid < 16) {
    float s = 0.f;
    #pragma unroll 8
    for (int k = 0; k < 32; ++k) s += ((float*)(lds + LDS_RED))[tid + 16 * k];
    const float v = s + bd[0];
    out[b0 + tid] = __builtin_amdgcn_rcpf(1.f + EXP2(-v * L2E));
  }
}

extern "C" void kernel_launch(void* const* d_in, const int* in_sizes, int n_in,
                              void* d_out, int out_size, void* d_ws, size_t ws_size,
                              hipStream_t stream) {
  const float* x    = (const float*)d_in[0];
  // d_in[1] = seq_lengths : unused by the reference
  const float* Wih0 = (const float*)d_in[2];
  const float* Whh0 = (const float*)d_in[3];
  const float* bih0 = (const float*)d_in[4];
  const float* bhh0 = (const float*)d_in[5];
  const float* Wih1 = (const float*)d_in[6];
  const float* Whh1 = (const float*)d_in[7];
  const float* bih1 = (const float*)d_in[8];
  const float* bhh1 = (const float*)d_in[9];
  const float* Wd   = (const float*)d_in[10];
  const float* bd   = (const float*)d_in[11];
  (void)in_sizes; (void)n_in; (void)out_size;

  if (ws_size >= WS_NEED && d_ws != nullptr) {
    lstm_zero_flags<<<dim3(8), dim3(256), 0, stream>>>((unsigned*)d_ws);
    lstm_split2<<<dim3(16), dim3(NTHR), 0, stream>>>(
        x, Wih0, Whh0, bih0, bhh0, Wih1, Whh1, bih1, bhh1, Wd, bd,
        (float*)d_out, (char*)d_ws);
  } else {
    lstm_single<<<dim3(16), dim3(NTHR), 0, stream>>>(
        x, Wih0, Whh0, bih0, bhh0, Wih1, Whh1, bih1, bhh1, Wd, bd, (float*)d_out);
  }
}